// Round 4
// baseline (581.367 us; speedup 1.0000x reference)
//
#include <hip/hip_runtime.h>
#include <hip/hip_bf16.h>
#include <cfloat>
#include <math.h>

// Problem: B=4,T=32,N=96,K=30, NUM_HIDDEN=128, NUM_IN=256, H=4, d=32
constexpr int SITES = 12288;
constexpr int KNB   = 30;
constexpr int CIN   = 256;
#define RSQRT_D 0.17677669529663689f

typedef short bf16x8 __attribute__((ext_vector_type(8)));   // 8 bf16 in 4 VGPRs
typedef float f32x4  __attribute__((ext_vector_type(4)));

__device__ inline unsigned short f2bs(float x) {
    __hip_bfloat16 b = __float2bfloat16(x);            // RTN-even
    return *(unsigned short*)&b;
}
__device__ inline float bs2f(unsigned short u) {
    unsigned int v = (unsigned int)u << 16;
    float f;
    __builtin_memcpy(&f, &v, 4);
    return f;
}
__device__ inline unsigned int pack2(float a, float b) {
    return (unsigned int)f2bs(a) | ((unsigned int)f2bs(b) << 16);
}

// ---------------------------------------------------------------------------
// Weight precompute (bf16, transposed for B^T GEMM):
//   Mt[(h*256+c)*128 + i] = sum_d Wq[i][h*32+d] * Wk[c][h*32+d]   (1024 x 128)
//   W3t[j*1024 + h*256+c] = sum_d Wv[c][h*32+d] * Wo[h*32+d][j]   (128 x 1024)
// ---------------------------------------------------------------------------
__global__ __launch_bounds__(256) void precompute_w(
    const float* __restrict__ Wq, const float* __restrict__ Wk,
    const float* __restrict__ Wv, const float* __restrict__ Wo,
    unsigned short* __restrict__ Mt, unsigned short* __restrict__ W3t) {
    int gid = blockIdx.x * 256 + threadIdx.x;
    if (gid < 131072) {
        int p = gid >> 7;          // h*256+c
        int i = gid & 127;
        int h = p >> 8;
        int c = p & 255;
        const float4* wq = (const float4*)(Wq + (size_t)i * 128 + h * 32);
        const float4* wk = (const float4*)(Wk + (size_t)c * 128 + h * 32);
        float s = 0.f;
        #pragma unroll
        for (int d = 0; d < 8; ++d) {
            float4 a = wq[d], b = wk[d];
            s += a.x * b.x; s += a.y * b.y; s += a.z * b.z; s += a.w * b.w;
        }
        Mt[gid] = f2bs(s);
    } else {
        int o = gid - 131072;
        int p = o >> 7;            // h*256+c  (wave-uniform)
        int j = o & 127;           // lanes vary j -> coalesced Wo
        int h = p >> 8;
        int c = p & 255;
        const float* wv = Wv + (size_t)c * 128 + h * 32;
        const float* wo = Wo + (size_t)(h * 32) * 128 + j;
        float s = 0.f;
        #pragma unroll
        for (int d = 0; d < 32; ++d)
            s += wv[d] * wo[(size_t)d * 128];
        W3t[(size_t)j * 1024 + p] = f2bs(s);
    }
}

// ---------------------------------------------------------------------------
// MEGA kernel: Q-projection + masked online-softmax attention + output
// projection, one block (256 thr = 4 waves) per 16 sites, grid 768.
//
//  Stage  : hV block (16x128 f32) -> hVs bf16 LDS (padded).
//  GEMM1  : qS[16][1024] = hVs @ Mt^T via MFMA; wave wv covers cols
//           wv*256..+255 (16 n-tiles x 4 k-steps = 64 MFMA/wave).
//           Mt (256 KB) read per block from L2.
//  Attn   : wave wv handles sites wv*4..+3 sequentially. Lane = (head
//           h=lane>>4, grp g=lane&15) owns 16 channels of ONE head ->
//           4-stage shuffle reduce (vs 24), 1 exp/row. Online softmax
//           (defer-max THR=8), hEV active rows read exactly once.
//  evbS   : [16][1024] bf16, 16B-unit XOR swizzle by (site&7) so GEMM2's
//           stride-2KB ds_read_b128 is conflict-free (T2).
//  GEMM2  : out(16x128) = evbS @ W3t^T; W3t (256 KB) from L2.
// ---------------------------------------------------------------------------
__global__ __launch_bounds__(256) void mega_fused(
    const float* __restrict__ hV, const float* __restrict__ hEV,
    const int* __restrict__ mask, const unsigned short* __restrict__ Mt,
    const unsigned short* __restrict__ W3t, float* __restrict__ out) {
    __shared__ __align__(16) unsigned short hVs[16][136];     // 4.25 KB (PAD 8)
    __shared__ __align__(16) unsigned short qS[16][1024];     // 32 KB
    __shared__ __align__(16) unsigned short evbS[16 * 1024];  // 32 KB
    const int tid  = threadIdx.x;
    const int lane = tid & 63;
    const int wv   = tid >> 6;
    const int quad = lane >> 4;
    const int l16  = lane & 15;
    const int s0   = blockIdx.x * 16;

    // ---- stage hV (16x128 f32 = 8 KB) -> bf16 LDS ----
    {
        const float4* src = (const float4*)(hV + (size_t)s0 * 128);
        float4 a = src[tid * 2], b = src[tid * 2 + 1];
        int site = tid >> 4, ch = (tid & 15) * 8;
        uint4 p;
        p.x = pack2(a.x, a.y); p.y = pack2(a.z, a.w);
        p.z = pack2(b.x, b.y); p.w = pack2(b.z, b.w);
        *(uint4*)&hVs[site][ch] = p;
    }
    __syncthreads();

    // ---- GEMM1: qS = hVs @ Mt^T (wave covers 256 cols) ----
    {
        const int n0 = wv * 256;
        f32x4 qa[16];
        #pragma unroll
        for (int j = 0; j < 16; ++j) qa[j] = (f32x4){0.f, 0.f, 0.f, 0.f};
        #pragma unroll
        for (int ks = 0; ks < 4; ++ks) {
            bf16x8 af = *(const bf16x8*)&hVs[l16][ks * 32 + quad * 8];
            #pragma unroll
            for (int j = 0; j < 16; ++j) {
                bf16x8 bfr = *(const bf16x8*)&Mt[(size_t)(n0 + j * 16 + l16) * 128
                                                 + ks * 32 + quad * 8];
                qa[j] = __builtin_amdgcn_mfma_f32_16x16x32_bf16(af, bfr, qa[j], 0, 0, 0);
            }
        }
        // C/D: col = l16 (n), row = quad*4 + r (site)
        #pragma unroll
        for (int j = 0; j < 16; ++j) {
            int col = n0 + j * 16 + l16;
            #pragma unroll
            for (int r = 0; r < 4; ++r) qS[quad * 4 + r][col] = f2bs(qa[j][r]);
        }
    }
    __syncthreads();

    // ---- attention: lane = (head h, grp g) owns 16 channels of head h ----
    const int h = lane >> 4;
    const int g = lane & 15;
    for (int si = 0; si < 4; ++si) {
        const int site = wv * 4 + si;
        const int s = s0 + site;

        int mk = (lane < KNB) ? mask[(size_t)s * KNB + lane] : 0;
        unsigned mw = (unsigned)__ballot(mk > 0) & 0x3FFFFFFFu;
        int na = __popc(mw);

        // q fragment: channels h*256 + g*16 .. +15 (bf16 -> f32)
        float qf[16];
        {
            const unsigned short* qr = &qS[site][h * 256 + g * 16];
            bf16x8 q0 = *(const bf16x8*)qr;
            bf16x8 q1 = *(const bf16x8*)(qr + 8);
            #pragma unroll
            for (int j = 0; j < 8; ++j) {
                qf[j]     = bs2f((unsigned short)q0[j]);
                qf[8 + j] = bs2f((unsigned short)q1[j]);
            }
        }

        float mh = -3.0e38f, lh = 0.f, acc[16];
        #pragma unroll
        for (int j = 0; j < 16; ++j) acc[j] = 0.f;

        const float* base = hEV + (size_t)s * (KNB * CIN) + g * 16;
        unsigned lmw = mw;
        float4 cur[4], nxt[4];
        if (na > 0) {
            int k = __builtin_ctz(lmw); lmw &= lmw - 1;
            const float* rp = base + (size_t)k * CIN;
            #pragma unroll
            for (int j = 0; j < 4; ++j) cur[j] = *(const float4*)(rp + j * 4);
        }
        for (int r = 0; r < na; ++r) {
            if (r + 1 < na) {                      // depth-2 pipeline
                int kn = __builtin_ctz(lmw); lmw &= lmw - 1;
                const float* rp = base + (size_t)kn * CIN;
                #pragma unroll
                for (int j = 0; j < 4; ++j) nxt[j] = *(const float4*)(rp + j * 4);
            }
            float lg = 0.f;
            #pragma unroll
            for (int j = 0; j < 4; ++j) {
                lg = fmaf(cur[j].x, qf[j * 4 + 0], lg);
                lg = fmaf(cur[j].y, qf[j * 4 + 1], lg);
                lg = fmaf(cur[j].z, qf[j * 4 + 2], lg);
                lg = fmaf(cur[j].w, qf[j * 4 + 3], lg);
            }
            lg += __shfl_xor(lg, 1, 64);
            lg += __shfl_xor(lg, 2, 64);
            lg += __shfl_xor(lg, 4, 64);
            lg += __shfl_xor(lg, 8, 64);
            float gv = lg * RSQRT_D;
            if (gv > mh + 8.f) {                   // defer-max rescale (T13)
                float sc = __expf(mh - gv);
                lh *= sc;
                #pragma unroll
                for (int j = 0; j < 16; ++j) acc[j] *= sc;
                mh = gv;
            }
            float p = __expf(gv - mh);             // bounded by e^8
            lh += p;
            #pragma unroll
            for (int j = 0; j < 4; ++j) {
                acc[j * 4 + 0] = fmaf(p, cur[j].x, acc[j * 4 + 0]);
                acc[j * 4 + 1] = fmaf(p, cur[j].y, acc[j * 4 + 1]);
                acc[j * 4 + 2] = fmaf(p, cur[j].z, acc[j * 4 + 2]);
                acc[j * 4 + 3] = fmaf(p, cur[j].w, acc[j * 4 + 3]);
            }
            #pragma unroll
            for (int j = 0; j < 4; ++j) cur[j] = nxt[j];
        }
        // evbS[site][h*256 + g*16 ..+15] = acc/l, bf16, 16B-swizzled
        float inv = (lh > 0.f) ? 1.f / lh : 0.f;
        unsigned pk[8];
        #pragma unroll
        for (int j = 0; j < 8; ++j) pk[j] = pack2(acc[2 * j] * inv, acc[2 * j + 1] * inv);
        const int swz = (site & 7) << 4;
        int b0 = (h * 512 + g * 32) ^ swz;
        int b1 = (h * 512 + g * 32 + 16) ^ swz;
        *(uint4*)((char*)evbS + site * 2048 + b0) = make_uint4(pk[0], pk[1], pk[2], pk[3]);
        *(uint4*)((char*)evbS + site * 2048 + b1) = make_uint4(pk[4], pk[5], pk[6], pk[7]);
    }
    __syncthreads();

    // ---- GEMM2: out(16x128) = evbS(16x1024) @ W3t^T ----
    const int n0 = wv * 32;                // wave covers 2 n-tiles (32 cols)
    f32x4 oacc0 = (f32x4){0.f, 0.f, 0.f, 0.f};
    f32x4 oacc1 = (f32x4){0.f, 0.f, 0.f, 0.f};
    const int aswz = (l16 & 7) << 4;
    #pragma unroll 4
    for (int kk = 0; kk < 1024; kk += 32) {
        int abyte = ((kk + quad * 8) * 2) ^ aswz;
        bf16x8 af = *(const bf16x8*)((const char*)evbS + l16 * 2048 + abyte);
        bf16x8 b0 = *(const bf16x8*)&W3t[(size_t)(n0 + l16) * 1024 + kk + quad * 8];
        bf16x8 b1 = *(const bf16x8*)&W3t[(size_t)(n0 + 16 + l16) * 1024 + kk + quad * 8];
        oacc0 = __builtin_amdgcn_mfma_f32_16x16x32_bf16(af, b0, oacc0, 0, 0, 0);
        oacc1 = __builtin_amdgcn_mfma_f32_16x16x32_bf16(af, b1, oacc1, 0, 0, 0);
    }
    // C/D layout: col = l16 (n), row = quad*4 + r (site)
    int srow = s0 + quad * 4;
    #pragma unroll
    for (int r = 0; r < 4; ++r) {
        out[(size_t)(srow + r) * 128 + n0 + l16]      = oacc0[r];
        out[(size_t)(srow + r) * 128 + n0 + 16 + l16] = oacc1[r];
    }
}

// ---------------------------------------------------------------------------
extern "C" void kernel_launch(void* const* d_in, const int* in_sizes, int n_in,
                              void* d_out, int out_size, void* d_ws, size_t ws_size,
                              hipStream_t stream) {
    const float* hV   = (const float*)d_in[0];
    const float* hEV  = (const float*)d_in[1];
    const int*   mask = (const int*)d_in[2];
    const float* Wq   = (const float*)d_in[3];
    const float* Wk   = (const float*)d_in[4];
    const float* Wv   = (const float*)d_in[5];
    const float* Wo   = (const float*)d_in[6];
    float* out = (float*)d_out;

    unsigned short* ws = (unsigned short*)d_ws;   // element = 2 B
    unsigned short* Mt   = ws;                    // 1024*128
    unsigned short* W3t  = ws + 131072;           // 128*1024
    size_t need = (size_t)262144 * 2;
    if (ws_size < need) return;

    precompute_w<<<dim3(1024), dim3(256), 0, stream>>>(Wq, Wk, Wv, Wo, Mt, W3t);

    // fused: Q-proj + masked attention + output projection
    mega_fused<<<dim3(SITES / 16), dim3(256), 0, stream>>>(
        hV, hEV, mask, Mt, W3t, out);
}